// Round 9
// baseline (2084.412 us; speedup 1.0000x reference)
//
#include <hip/hip_runtime.h>

namespace {
constexpr int Tn = 4096;
constexpr int Kn = 64;
constexpr int BATCH = 128;
constexpr int START_TAG = 62;
constexpr int STOP_TAG = 63;
constexpr float NEGV = -10000.0f;
constexpr int CH = 64;          // backtrace chunk length
constexpr int NCH = Tn / CH;    // 64 chunks
constexpr int GL = 8;           // feats burst length
constexpr int NG = Tn / GL;     // 512 groups
constexpr int WV = 4;           // waves per block
constexpr int SL = Kn / WV;     // 16 prev-states per wave
constexpr int KP = 66;          // padded partial stride

__device__ __forceinline__ float rfl(float x) {
    return __uint_as_float(__builtin_amdgcn_readfirstlane(__float_as_uint(x)));
}
// wave-uniform register broadcast (no LDS): readlane -> SGPR
__device__ __forceinline__ float bcast(float v, int i) {
    return __int_as_float(__builtin_amdgcn_readlane(__float_as_int(v), i));
}
// LDS-only barrier: waits lgkmcnt but NOT vmcnt, so global bursts stay in flight.
__device__ __forceinline__ void bar() {
    __asm__ volatile("s_waitcnt lgkmcnt(0)\n\ts_barrier" ::: "memory");
}
__device__ __forceinline__ void vmdrain() {
    __asm__ volatile("s_waitcnt vmcnt(0)" ::: "memory");
}
// monotone float->u32 map (preserves fp32 ordering exactly)
__device__ __forceinline__ unsigned int fkey(float x) {
    unsigned int b = __float_as_uint(x);
    return (b & 0x80000000u) ? ~b : (b | 0x80000000u);
}
__device__ __forceinline__ float unkey(unsigned int hb) {
    return __uint_as_float((hb & 0x80000000u) ? (hb ^ 0x80000000u) : ~hb);
}

__global__ __launch_bounds__(256)
void crf_kernel(const float* __restrict__ feats,   // [B,T,K]
                const int* __restrict__ tags,      // [B,T]
                const float* __restrict__ trans,   // [K,K]  trans[next,prev]
                float* __restrict__ out,           // [B] nll | [B] path_score | [B,T] path
                unsigned int* __restrict__ bp32)   // [B,T/4,K] packed backpointers
{
    const int tid = threadIdx.x;
    const int lane = tid & 63;
    const int wid = tid >> 6;
    const int b = blockIdx.x & (BATCH - 1);
    const size_t fb = (size_t)b * Tn * Kn;

    __shared__ float wp[2][WV * KP];              // fwd partial sums
    __shared__ unsigned long long kp[2][WV * KP]; // vit partial keys
    __shared__ float gw[WV];                      // gold partial per wave
    __shared__ unsigned char snap[NCH * Kn];
    __shared__ unsigned char echain[NCH];

    if (blockIdx.x < BATCH) {
        // ================= forward log-partition + gold -> nll =================
        // ---- gold: 256 threads x 16 steps each ----
        {
            float gold = 0.0f;
            const int t0 = tid * (Tn / 256);
            int prev = (tid == 0) ? START_TAG : tags[(size_t)b * Tn + t0 - 1];
            for (int k = 0; k < Tn / 256; ++k) {
                const int t = t0 + k;
                const int tg = tags[(size_t)b * Tn + t];
                gold += trans[tg * Kn + prev] + feats[fb + (size_t)t * Kn + tg];
                prev = tg;
            }
            if (tid == 255) gold += trans[STOP_TAG * Kn + prev];
            #pragma unroll
            for (int off = 32; off; off >>= 1) gold += __shfl_down(gold, off);
            if (lane == 0) gw[wid] = gold;  // read after loop (4096 bars in between)
        }
        // slice of exp(trans): ES[s] = exp(trans[lane, wid*16+s])
        float ES[SL];
        #pragma unroll
        for (int q = 0; q < SL / 4; ++q) {
            const float4 t4 = ((const float4*)(trans + lane * Kn + wid * SL))[q];
            ES[4*q+0] = __expf(t4.x); ES[4*q+1] = __expf(t4.y);
            ES[4*q+2] = __expf(t4.z); ES[4*q+3] = __expf(t4.w);
        }
        // exp-domain one-hot init, broadcast slice in registers (uniform -> SGPR)
        float bc[SL];
        #pragma unroll
        for (int q = 0; q < SL; ++q)
            bc[q] = (wid * SL + q == START_TAG) ? 1.0f : 0.0f;
        float O = 0.0f, v = 0.0f;

        float fc[GL], fn[GL], Fc[GL];
        #pragma unroll
        for (int k = 0; k < GL; ++k) fc[k] = feats[fb + (size_t)k * Kn + lane];
        for (int g = 0; g < NG; ++g) {
            if (g + 1 < NG) {
                const size_t base = fb + (size_t)(g + 1) * GL * Kn + lane;
                #pragma unroll
                for (int k = 0; k < GL; ++k) fn[k] = feats[base + (size_t)k * Kn];
            }
            #pragma unroll
            for (int k = 0; k < GL; ++k) Fc[k] = __expf(fc[k]);
            #pragma unroll
            for (int k = 0; k < GL; ++k) {
                const int t = g * GL + k;
                const int p = t & 1;
                // ---- phase A: partial dot over this wave's 16 prev states,
                //      operands from SGPR broadcasts (no LDS round-trip) ----
                float s0 = 0.f, s1 = 0.f, s2 = 0.f, s3 = 0.f;
                #pragma unroll
                for (int q = 0; q < 4; ++q) {
                    s0 = fmaf(ES[4*q+0], bc[4*q+0], s0);
                    s1 = fmaf(ES[4*q+1], bc[4*q+1], s1);
                    s2 = fmaf(ES[4*q+2], bc[4*q+2], s2);
                    s3 = fmaf(ES[4*q+3], bc[4*q+3], s3);
                }
                wp[p][wid * KP + lane] = (s0 + s1) + (s2 + s3);
                bar();                           // the ONLY barrier per step
                // ---- phase B: combine 4 partials (fixed order), renormalize,
                //      re-broadcast via readlane (registers only) ----
                const float w0r = wp[p][0 * KP + lane];
                const float w1r = wp[p][1 * KP + lane];
                const float w2r = wp[p][2 * KP + lane];
                const float w3r = wp[p][3 * KP + lane];
                const float w = ((w0r + w1r) + (w2r + w3r)) * Fc[k];
                const float wz = rfl(w);         // lane-0 value > 0
                O += __logf(wz);                 // off-chain log accumulation
                v = w * __builtin_amdgcn_rcpf(wz);
                #pragma unroll
                for (int q = 0; q < SL; ++q) bc[q] = bcast(v, wid * SL + q);
            }
            #pragma unroll
            for (int k = 0; k < GL; ++k) fc[k] = fn[k];
        }
        // ---- nll = logsumexp(alpha + trans[STOP,:]) - gold (wave 0 writes) ----
        if (wid == 0) {
            const float a = O + __logf(v);       // v==0 -> -inf, fine
            const float x = a + trans[STOP_TAG * Kn + lane];
            float mx = x;
            #pragma unroll
            for (int off = 32; off; off >>= 1) mx = fmaxf(mx, __shfl_xor(mx, off));
            float se = __expf(x - mx);
            #pragma unroll
            for (int off = 32; off; off >>= 1) se += __shfl_xor(se, off);
            if (lane == 0)
                out[b] = (mx + __logf(se)) - (((gw[0] + gw[1]) + (gw[2] + gw[3])));
        }
    } else {
        // ================= Viterbi decode (exact fp32) =================
        float trS[SL];
        #pragma unroll
        for (int q = 0; q < SL / 4; ++q) {
            const float4 t4 = ((const float4*)(trans + lane * Kn + wid * SL))[q];
            trS[4*q+0] = t4.x; trS[4*q+1] = t4.y;
            trS[4*q+2] = t4.z; trS[4*q+3] = t4.w;
        }
        float bc[SL];
        #pragma unroll
        for (int q = 0; q < SL; ++q)
            bc[q] = (wid * SL + q == START_TAG) ? 0.0f : NEGV;
        float d = 0.0f;
        int h = lane;
        unsigned int bp4 = 0;
        const size_t dwb = (size_t)b * (Tn / 4);

        float fc[GL], fn[GL];
        #pragma unroll
        for (int k = 0; k < GL; ++k) fc[k] = feats[fb + (size_t)k * Kn + lane];
        for (int g = 0; g < NG; ++g) {
            if (g + 1 < NG) {
                const size_t base = fb + (size_t)(g + 1) * GL * Kn + lane;
                #pragma unroll
                for (int k = 0; k < GL; ++k) fn[k] = feats[base + (size_t)k * Kn];
            }
            #pragma unroll
            for (int k = 0; k < GL; ++k) {
                const int t = g * GL + k;
                const int p = t & 1;
                // ---- phase A: slice max+argmax from SGPR broadcasts ----
                float gv[4]; int gi[4];
                #pragma unroll
                for (int q = 0; q < 4; ++q) {
                    const int i0 = wid * SL + 4 * q;
                    const float sx = bc[4*q+0] + trS[4*q+0];
                    const float sy = bc[4*q+1] + trS[4*q+1];
                    const float sz = bc[4*q+2] + trS[4*q+2];
                    const float sw = bc[4*q+3] + trS[4*q+3];
                    const bool c01 = sy > sx;
                    const float v01 = c01 ? sy : sx; const int i01 = c01 ? i0+1 : i0;
                    const bool c23 = sw > sz;
                    const float v23 = c23 ? sw : sz; const int i23 = c23 ? i0+3 : i0+2;
                    const bool cq = v23 > v01;
                    gv[q] = cq ? v23 : v01; gi[q] = cq ? i23 : i01;
                }
                const bool ca = gv[1] > gv[0];
                const float va = ca ? gv[1] : gv[0]; const int ia = ca ? gi[1] : gi[0];
                const bool cb = gv[3] > gv[2];
                const float vb = cb ? gv[3] : gv[2]; const int ib = cb ? gi[3] : gi[2];
                const bool cm = vb > va;
                const float m = cm ? vb : va; const int li = cm ? ib : ia;
                // pack: value (monotone) hi32, (63-idx) lo32 -> u64 max == first-max
                kp[p][wid * KP + lane] =
                    ((unsigned long long)fkey(m) << 32) | (unsigned long long)(63 - li);
                bar();                           // the ONLY barrier per step
                // ---- phase B: combine 4 partial keys, re-broadcast state ----
                const unsigned long long k0 = kp[p][0 * KP + lane];
                const unsigned long long k1 = kp[p][1 * KP + lane];
                const unsigned long long k2 = kp[p][2 * KP + lane];
                const unsigned long long k3 = kp[p][3 * KP + lane];
                const unsigned long long ka = k0 > k1 ? k0 : k1;
                const unsigned long long kb = k2 > k3 ? k2 : k3;
                const unsigned long long km = ka > kb ? ka : kb;
                const int bp = 63 - (int)(unsigned int)(km & 0xffffffffULL);
                d = unkey((unsigned int)(km >> 32)) + fc[k];  // feat after argmax
                #pragma unroll
                for (int q = 0; q < SL; ++q) bc[q] = bcast(d, wid * SL + q);
                if (wid == 3) {
                    if ((k & 3) == 0) bp4 = (unsigned int)bp;
                    else bp4 |= (unsigned int)bp << (8 * (k & 3));
                    if ((k & 3) == 3)
                        bp32[(dwb + (size_t)(2 * g + (k >> 2))) * Kn + lane] = bp4;
                    h = __shfl(h, bp);
                    if ((t & (CH - 1)) == (CH - 1)) {
                        snap[(t >> 6) * Kn + lane] = (unsigned char)h;
                        h = lane;
                    }
                }
            }
            #pragma unroll
            for (int k = 0; k < GL; ++k) fc[k] = fn[k];
        }
        vmdrain();   // bp32 stores (wave 3) land before backtrace reads
        // ---- terminal argmax (first index on ties), wave 3 ----
        if (wid == 3) {
            const float term = d + trans[STOP_TAG * Kn + lane];
            float bv = term;
            int bi = lane;
            #pragma unroll
            for (int off = 32; off; off >>= 1) {
                const float ov = __shfl_xor(bv, off);
                const int oi = __shfl_xor(bi, off);
                if (ov > bv || (ov == bv && oi < bi)) { bv = ov; bi = oi; }
            }
            if (lane == 0) {
                out[BATCH + b] = bv;
                int e = bi;
                for (int c = NCH - 1; c >= 0; --c) {
                    echain[c] = (unsigned char)e;
                    e = snap[c * Kn + e];
                }
            }
        }
        bar();
        // ---- within-chunk reconstruction: wave 0, lane = chunk ----
        if (wid == 0) {
            int tag = echain[lane];
            float* po = out + 2 * BATCH + (size_t)b * Tn;
            for (int k = CH - 1; k >= 0; --k) {
                const int t = lane * CH + k;
                po[t] = (float)tag;
                tag = (int)((bp32[(dwb + (size_t)(t >> 2)) * Kn + tag] >> (8 * (t & 3))) & 63u);
            }
        }
    }
}
} // namespace

extern "C" void kernel_launch(void* const* d_in, const int* in_sizes, int n_in,
                              void* d_out, int out_size, void* d_ws, size_t ws_size,
                              hipStream_t stream)
{
    const float* feats = (const float*)d_in[0];
    const int* tags   = (const int*)d_in[1];
    const float* trans = (const float*)d_in[2];
    float* out = (float*)d_out;
    unsigned int* bp = (unsigned int*)d_ws;  // needs 128*4096*64 B = 32 MB
    hipLaunchKernelGGL(crf_kernel, dim3(2 * BATCH), dim3(256), 0, stream,
                       feats, tags, trans, out, bp);
}